// Round 5
// baseline (2219.404 us; speedup 1.0000x reference)
//
#include <hip/hip_runtime.h>
#include <hip/hip_bf16.h>
#include <math.h>

#define NB 4
#define SEQ 1024
#define DM 512
#define DB 256
#define G3 768
#define CO 32
#define TONS 8192
#define POOLN 8
#define TOCT 1024
#define NH 8
#define DHD 32

// workspace float offsets
#define OFF_GI     0u            // 4096*768
#define OFF_GIBAR  3145728u      // 4096*768
#define OFF_HEND   6291456u      // 4096*256
#define OFF_GALL   7340032u      // 4096*256
#define OFF_KMAT   8388608u      // 4096*256
#define OFF_WPN    9437184u      // 98304 uints (packed bf16 Whh_note)
#define OFF_WPB    9633792u      // 98304 uints (packed bf16 Whh_bar)
#define OFF_INT_BYTES 39321600u  // ints after floats

#define OUT_FINAL 4096
#define OUT_CARR  5120

__device__ __forceinline__ unsigned int bf16rne(float f) {
    unsigned int u = __float_as_uint(f);
    return (u + 0x7fffu + ((u >> 16) & 1u)) >> 16;
}
__device__ __forceinline__ float lof(unsigned int u) { return __uint_as_float(u << 16); }
__device__ __forceinline__ float hif(unsigned int u) { return __uint_as_float(u & 0xffff0000u); }

// ---------- K0: mask dtype detection + per-batch mask scan ----------
__global__ __launch_bounds__(256) void k_scan(const unsigned char* __restrict__ mraw,
        int* __restrict__ pos, int* __restrict__ lastk, int* __restrict__ nmask) {
    __shared__ int rnz[8];
    __shared__ int gt1;
    __shared__ int mode;
    int tid = threadIdx.x;
    if (tid < 8) rnz[tid] = 0;
    if (tid == 0) gt1 = 0;
    __syncthreads();
    for (int i = tid; i < NB * SEQ; i += 256) {
        unsigned char v = mraw[i];
        if (v) {
            rnz[i & 7] = 1;          // benign same-value race
            if (v > 1) gt1 = 1;
        }
    }
    __syncthreads();
    if (tid == 0) {
        bool lowhalf = rnz[0] | rnz[1] | rnz[4] | rnz[5];
        bool hihalf  = rnz[2] | rnz[3] | rnz[6] | rnz[7];
        int m;
        if (hihalf && !lowhalf) {
            m = (rnz[2] | rnz[3]) ? 3 : 4;          // f32 : f64
        } else if (gt1) {
            m = 5;                                   // 16-bit float-ish
        } else if (rnz[1] | rnz[3] | rnz[5] | rnz[7]) {
            m = 0;                                   // u8 bool
        } else if (rnz[4]) {
            m = 1;                                   // i32
        } else if (rnz[0]) {
            m = 2;                                   // i64
        } else {
            m = 0;
        }
        mode = m;
    }
    __syncthreads();
    if (tid < NB) {
        int b = tid;
        int cnt = 0;
        for (int t = 0; t < SEQ; ++t) {
            int idx = b * SEQ + t;
            int mv;
            switch (mode) {
                case 0:  mv = mraw[idx] != 0; break;
                case 1:  mv = ((const int*)mraw)[idx] != 0; break;
                case 2:  mv = ((const long long*)mraw)[idx] != 0LL; break;
                case 3:  mv = ((const float*)mraw)[idx] != 0.f; break;
                case 4:  mv = ((const double*)mraw)[idx] != 0.0; break;
                default: mv = ((const unsigned short*)mraw)[idx] != 0; break;
            }
            if (mv) { pos[b * SEQ + cnt] = t; ++cnt; }
            lastk[idx] = cnt - 1;
        }
        nmask[b] = cnt;
    }
}

// ---------- pack Whh (768x256 f32) -> bf16x2 uint, uint4-friendly layout ----------
// uint linear index i: r4 = i/3072; row = (i%3072)>>2; j = i&3; r = 4*r4+j;
// packs W[row][2r] (lo) | W[row][2r+1] (hi). Thread tid's 32 uint4 loads are
// Wp4[r4*768 + tid], coalesced across tid.
__global__ __launch_bounds__(256) void k_pack(const float* __restrict__ W, unsigned int* __restrict__ out) {
    int i = blockIdx.x * 256 + threadIdx.x;
    if (i >= 128 * G3) return;
    int r4 = i / 3072;
    int rem = i % 3072;
    int row = rem >> 2;
    int j = rem & 3;
    int r = 4 * r4 + j;
    unsigned int lo = bf16rne(W[(size_t)row * DB + 2 * r]);
    unsigned int hi = bf16rne(W[(size_t)row * DB + 2 * r + 1]);
    out[i] = lo | (hi << 16);
}

// ---------- tiled NT GEMM: C[m][n] = bias[n] + sum_k A[m*K+k]*Bm[n*K+k] ----------
__global__ __launch_bounds__(256) void k_gemm_nt(int M, int N, int K,
        const float* __restrict__ A, const float* __restrict__ Bm,
        const float* __restrict__ bias, float* __restrict__ C) {
    __shared__ __align__(16) float As2[32][68];
    __shared__ __align__(16) float Bs2[32][68];
    int bm = blockIdx.y * 64, bn = blockIdx.x * 64;
    int tid = threadIdx.x;
    int tx = tid & 15, ty = tid >> 4;
    float acc[4][4] = {};
    for (int k0 = 0; k0 < K; k0 += 32) {
        for (int i = tid; i < 64 * 32; i += 256) {
            int r = i >> 5, c = i & 31;
            As2[c][r] = A[(size_t)(bm + r) * K + k0 + c];
            Bs2[c][r] = Bm[(size_t)(bn + r) * K + k0 + c];
        }
        __syncthreads();
#pragma unroll
        for (int kk = 0; kk < 32; ++kk) {
            float4 av = *reinterpret_cast<const float4*>(&As2[kk][ty * 4]);
            float4 bv = *reinterpret_cast<const float4*>(&Bs2[kk][tx * 4]);
            float a[4] = {av.x, av.y, av.z, av.w};
            float b[4] = {bv.x, bv.y, bv.z, bv.w};
#pragma unroll
            for (int i = 0; i < 4; ++i)
#pragma unroll
                for (int j = 0; j < 4; ++j) acc[i][j] += a[i] * b[j];
        }
        __syncthreads();
    }
#pragma unroll
    for (int i = 0; i < 4; ++i)
#pragma unroll
        for (int j = 0; j < 4; ++j)
            C[(size_t)(bm + ty * 4 + i) * N + bn + tx * 4 + j] = acc[i][j] + bias[bn + tx * 4 + j];
}

// ---------- K matrix: pooled onset + sinusoidal PE, project 32->256 ----------
__global__ __launch_bounds__(64) void k_keys(const float* __restrict__ onset,
        const float* __restrict__ Wk, const float* __restrict__ bk, float* __restrict__ Kmat) {
    int bt = blockIdx.x;
    int b = bt >> 10, t = bt & 1023;
    __shared__ float xin[CO];
    int tid = threadIdx.x;
    if (tid < CO) {
        float s = 0.f;
        const float* base = onset + ((size_t)b * TONS + (size_t)t * POOLN) * CO + tid;
#pragma unroll
        for (int p = 0; p < POOLN; ++p) s += base[p * CO];
        s *= (1.f / POOLN);
        int j = tid >> 1;
        float dv = expf(-logf(10000.f) * (float)j / 16.f);
        float ang = (float)t * dv;
        s += (tid & 1) ? cosf(ang) : sinf(ang);
        xin[tid] = s;
    }
    __syncthreads();
    for (int n = tid; n < DB; n += 64) {
        float acc = bk[n];
        const float* wr = Wk + (size_t)n * CO;
#pragma unroll
        for (int c = 0; c < CO; ++c) acc += xin[c] * wr[c];
        Kmat[(size_t)bt * DB + n] = acc;
    }
}

// 32 named uint4 weight registers: fully static declare/load/use.
#define W_DECL(i) uint4 w##i = Wp4[(i) * G3 + tid];
#define W_DOT(i) { \
    float4 hv0 = h4[2 * (i)]; \
    float4 hv1 = h4[2 * (i) + 1]; \
    ax += lof(w##i.x) * hv0.x; ay += hif(w##i.x) * hv0.y; \
    ax += lof(w##i.y) * hv0.z; ay += hif(w##i.y) * hv0.w; \
    ax += lof(w##i.z) * hv1.x; ay += hif(w##i.z) * hv1.y; \
    ax += lof(w##i.w) * hv1.z; ay += hif(w##i.w) * hv1.w; }

#define W_ALL(OP) OP(0) OP(1) OP(2) OP(3) OP(4) OP(5) OP(6) OP(7) \
    OP(8) OP(9) OP(10) OP(11) OP(12) OP(13) OP(14) OP(15) \
    OP(16) OP(17) OP(18) OP(19) OP(20) OP(21) OP(22) OP(23) \
    OP(24) OP(25) OP(26) OP(27) OP(28) OP(29) OP(30) OP(31)

// ---------- phase B: per-chain note-GRU rollout, bf16 Whh in named registers ----------
__global__ __launch_bounds__(768, 1) void k_noteg(const uint4* __restrict__ Wp4,
        const float* __restrict__ bhh, const float* __restrict__ gi,
        const int* __restrict__ pos, const int* __restrict__ nmask, float* __restrict__ hend) {
    int c = blockIdx.x;
    int b = c >> 10, k = c & 1023;
    if (k >= nmask[b]) return;
    int s = (k == 0) ? 0 : pos[b * SEQ + k - 1] + 1;
    int e = pos[b * SEQ + k];
    int tid = threadIdx.x;
    __shared__ __align__(16) float hs[DB];
    __shared__ float ghs[G3];
    __shared__ float gxs[G3];
    W_ALL(W_DECL)
    float bh = bhh[tid];
    float h_reg = 0.f;
    if (tid < DB) hs[tid] = 0.f;
    __syncthreads();
    const float4* h4 = (const float4*)hs;
    const float* gip = gi + (size_t)(b * SEQ + s) * G3 + tid;
    for (int t = s; t < e; ++t) {
        float gpre = *gip;
        gip += G3;
        float ax = 0.f, ay = 0.f;
        if (t != s) {
            W_ALL(W_DOT)
        }
        ghs[tid] = bh + ax + ay;
        gxs[tid] = gpre;
        __syncthreads();
        if (tid < DB) {
            float r = 1.f / (1.f + expf(-(gxs[tid] + ghs[tid])));
            float z = 1.f / (1.f + expf(-(gxs[DB + tid] + ghs[DB + tid])));
            float n = tanhf(gxs[2 * DB + tid] + r * ghs[2 * DB + tid]);
            h_reg = (1.f - z) * n + z * h_reg;
            hs[tid] = h_reg;
        }
        __syncthreads();
    }
    if (tid < DB) hend[(size_t)c * DB + tid] = h_reg;
}

// ---------- phase C: per-batch bar-GRU chain, bf16 Whh in named registers ----------
__global__ __launch_bounds__(768, 1) void k_barg(const uint4* __restrict__ Wp4,
        const float* __restrict__ bhh, const float* __restrict__ gibar,
        const int* __restrict__ nmask, float* __restrict__ gall) {
    int b = blockIdx.x;
    int nm = nmask[b];
    int tid = threadIdx.x;
    __shared__ __align__(16) float hs[DB];
    __shared__ float ghs[G3];
    __shared__ float gxs[G3];
    W_ALL(W_DECL)
    float bh = bhh[tid];
    float g_reg = 0.f;
    if (tid < DB) hs[tid] = 0.f;
    __syncthreads();
    const float4* h4 = (const float4*)hs;
    const float* gip = gibar + (size_t)(b * SEQ) * G3 + tid;
    for (int k = 0; k < nm; ++k) {
        float gpre = *gip;
        gip += G3;
        float ax = 0.f, ay = 0.f;
        if (k != 0) {
            W_ALL(W_DOT)
        }
        ghs[tid] = bh + ax + ay;
        gxs[tid] = gpre;
        __syncthreads();
        if (tid < DB) {
            float r = 1.f / (1.f + expf(-(gxs[tid] + ghs[tid])));
            float z = 1.f / (1.f + expf(-(gxs[DB + tid] + ghs[DB + tid])));
            float n = tanhf(gxs[2 * DB + tid] + r * ghs[2 * DB + tid]);
            g_reg = (1.f - z) * n + z * g_reg;
            hs[tid] = g_reg;
            gall[(size_t)(b * SEQ + k) * DB + tid] = g_reg;
        }
        __syncthreads();
    }
}

// ---------- fill outputs: h_bar_carried, h_bar_final, zero com ----------
__global__ __launch_bounds__(256) void k_fill(const float* __restrict__ gall,
        const int* __restrict__ lastk, const int* __restrict__ nmask,
        float* __restrict__ out) {
    int bt = blockIdx.x;
    int b = bt >> 10, t = bt & 1023;
    int tid = threadIdx.x;
    int lk = lastk[bt];
    float v = (lk >= 0) ? gall[((size_t)b * SEQ + lk) * DB + tid] : 0.f;
    out[OUT_CARR + (size_t)bt * DB + tid] = v;
    if (tid == 0) out[bt] = 0.f;
    if (t == 0) {
        int nm = nmask[b];
        float fv = (nm > 0) ? gall[((size_t)b * SEQ + nm - 1) * DB + tid] : 0.f;
        out[OUT_FINAL + b * DB + tid] = fv;
    }
}

// ---------- attention + com at mask rows only ----------
__global__ __launch_bounds__(256) void k_attn(const float* __restrict__ gall,
        const float* __restrict__ Wq, const float* __restrict__ bq,
        const float* __restrict__ Kmat, const int* __restrict__ pos,
        const int* __restrict__ nmask, const float* __restrict__ pbs_ptr,
        float* __restrict__ out) {
    int c = blockIdx.x;
    int b = c >> 10, k = c & 1023;
    if (k >= nmask[b]) return;
    int trow = pos[b * SEQ + k];
    __shared__ float q[DB];
    __shared__ float grow[DB];
    __shared__ float sc[NH][TOCT];
    __shared__ float comh[NH];
    int tid = threadIdx.x;
    grow[tid] = gall[((size_t)b * SEQ + k) * DB + tid];
    __syncthreads();
    {
        float acc = bq[tid];
        const float* wr = Wq + (size_t)tid * DB;
#pragma unroll 4
        for (int j = 0; j < DB; ++j) acc += grow[j] * wr[j];
        q[tid] = acc;
    }
    __syncthreads();
    float pbs = *pbs_ptr;
    const float scale = 0.17677669529663687f; // 1/sqrt(32)
    for (int t = tid; t < TOCT; t += 256) {
        const float* kr = Kmat + ((size_t)b * TOCT + t) * DB;
        float tp = (float)t * (1.f / 1023.f);
#pragma unroll
        for (int h = 0; h < NH; ++h) {
            float acc = 0.f;
#pragma unroll
            for (int d = 0; d < DHD; ++d) acc += q[h * DHD + d] * kr[h * DHD + d];
            sc[h][t] = acc * scale - pbs * tp;
        }
    }
    __syncthreads();
    int hh = tid >> 5, l = tid & 31;
    float mx = -1e30f;
    for (int t = l; t < TOCT; t += 32) mx = fmaxf(mx, sc[hh][t]);
#pragma unroll
    for (int o = 16; o > 0; o >>= 1) mx = fmaxf(mx, __shfl_xor(mx, o, 32));
    float se = 0.f, sw = 0.f;
    for (int t = l; t < TOCT; t += 32) {
        float e = expf(sc[hh][t] - mx);
        se += e;
        sw += e * ((float)t * (1.f / 1023.f));
    }
#pragma unroll
    for (int o = 16; o > 0; o >>= 1) { se += __shfl_xor(se, o, 32); sw += __shfl_xor(sw, o, 32); }
    if (l == 0) comh[hh] = sw / se;
    __syncthreads();
    if (tid == 0) {
        float cm = 0.f;
#pragma unroll
        for (int h = 0; h < NH; ++h) cm += comh[h];
        out[b * SEQ + trow] = cm * (1.f / NH);
    }
}

extern "C" void kernel_launch(void* const* d_in, const int* in_sizes, int n_in,
                              void* d_out, int out_size, void* d_ws, size_t ws_size,
                              hipStream_t stream) {
    const float* te    = (const float*)d_in[0];
    const float* onset = (const float*)d_in[1];
    const unsigned char* mask = (const unsigned char*)d_in[2];
    const float* Wih_n = (const float*)d_in[3];
    const float* Whh_n = (const float*)d_in[4];
    const float* bih_n = (const float*)d_in[5];
    const float* bhh_n = (const float*)d_in[6];
    const float* Wih_b = (const float*)d_in[7];
    const float* Whh_b = (const float*)d_in[8];
    const float* bih_b = (const float*)d_in[9];
    const float* bhh_b = (const float*)d_in[10];
    const float* Wq    = (const float*)d_in[11];
    const float* bq    = (const float*)d_in[12];
    const float* Wk    = (const float*)d_in[13];
    const float* bk    = (const float*)d_in[14];
    const float* pbs   = (const float*)d_in[15];
    float* out = (float*)d_out;

    float* ws    = (float*)d_ws;
    float* gi    = ws + OFF_GI;
    float* gibar = ws + OFF_GIBAR;
    float* hend  = ws + OFF_HEND;
    float* gall  = ws + OFF_GALL;
    float* kmat  = ws + OFF_KMAT;
    unsigned int* wpn = (unsigned int*)(ws + OFF_WPN);
    unsigned int* wpb = (unsigned int*)(ws + OFF_WPB);
    int* ipos    = (int*)((char*)d_ws + OFF_INT_BYTES);
    int* ilastk  = ipos + NB * SEQ;
    int* inmask  = ilastk + NB * SEQ;

    k_scan<<<1, 256, 0, stream>>>(mask, ipos, ilastk, inmask);
    k_pack<<<384, 256, 0, stream>>>(Whh_n, wpn);
    k_pack<<<384, 256, 0, stream>>>(Whh_b, wpb);
    k_gemm_nt<<<dim3(G3 / 64, (NB * SEQ) / 64), 256, 0, stream>>>(NB * SEQ, G3, DM, te, Wih_n, bih_n, gi);
    k_keys<<<NB * TOCT, 64, 0, stream>>>(onset, Wk, bk, kmat);
    k_noteg<<<NB * SEQ, 768, 0, stream>>>((const uint4*)wpn, bhh_n, gi, ipos, inmask, hend);
    k_gemm_nt<<<dim3(G3 / 64, (NB * SEQ) / 64), 256, 0, stream>>>(NB * SEQ, G3, DB, hend, Wih_b, bih_b, gibar);
    k_barg<<<NB, 768, 0, stream>>>((const uint4*)wpb, bhh_b, gibar, inmask, gall);
    k_fill<<<NB * SEQ, 256, 0, stream>>>(gall, ilastk, inmask, out);
    k_attn<<<NB * SEQ, 256, 0, stream>>>(gall, Wq, bq, kmat, ipos, inmask, pbs, out);
}

// Round 6
// 1460.481 us; speedup vs baseline: 1.5196x; 1.5196x over previous
//
#include <hip/hip_runtime.h>
#include <hip/hip_bf16.h>
#include <math.h>

#define NB 4
#define SEQ 1024
#define DM 512
#define DB 256
#define G3 768
#define CO 32
#define TONS 8192
#define POOLN 8
#define TOCT 1024
#define NH 8
#define DHD 32

// workspace float offsets
#define OFF_GI     0u            // 4096*768
#define OFF_GIBAR  3145728u      // 4096*768
#define OFF_HEND   6291456u      // 4096*256
#define OFF_GALL   7340032u      // 4096*256
#define OFF_KMAT   8388608u      // 4096*256
#define OFF_WPN    9437184u      // 98304 uints (packed bf16 Whh_note, col-major pairs)
#define OFF_WPB    9633792u      // 98304 uints (packed bf16 Whh_bar)
#define OFF_INT_BYTES 39321600u  // ints after floats

#define OUT_FINAL 4096
#define OUT_CARR  5120

__device__ __forceinline__ unsigned int bf16rne(float f) {
    unsigned int u = __float_as_uint(f);
    return (u + 0x7fffu + ((u >> 16) & 1u)) >> 16;
}
__device__ __forceinline__ float lof(unsigned int u) { return __uint_as_float(u << 16); }
__device__ __forceinline__ float hif(unsigned int u) { return __uint_as_float(u & 0xffff0000u); }

// ---------- K0: mask dtype detection + per-batch mask scan ----------
__global__ __launch_bounds__(256) void k_scan(const unsigned char* __restrict__ mraw,
        int* __restrict__ pos, int* __restrict__ lastk, int* __restrict__ nmask) {
    __shared__ int rnz[8];
    __shared__ int gt1;
    __shared__ int mode;
    int tid = threadIdx.x;
    if (tid < 8) rnz[tid] = 0;
    if (tid == 0) gt1 = 0;
    __syncthreads();
    for (int i = tid; i < NB * SEQ; i += 256) {
        unsigned char v = mraw[i];
        if (v) {
            rnz[i & 7] = 1;          // benign same-value race
            if (v > 1) gt1 = 1;
        }
    }
    __syncthreads();
    if (tid == 0) {
        bool lowhalf = rnz[0] | rnz[1] | rnz[4] | rnz[5];
        bool hihalf  = rnz[2] | rnz[3] | rnz[6] | rnz[7];
        int m;
        if (hihalf && !lowhalf) {
            m = (rnz[2] | rnz[3]) ? 3 : 4;          // f32 : f64
        } else if (gt1) {
            m = 5;                                   // 16-bit float-ish
        } else if (rnz[1] | rnz[3] | rnz[5] | rnz[7]) {
            m = 0;                                   // u8 bool
        } else if (rnz[4]) {
            m = 1;                                   // i32
        } else if (rnz[0]) {
            m = 2;                                   // i64
        } else {
            m = 0;
        }
        mode = m;
    }
    __syncthreads();
    if (tid < NB) {
        int b = tid;
        int cnt = 0;
        for (int t = 0; t < SEQ; ++t) {
            int idx = b * SEQ + t;
            int mv;
            switch (mode) {
                case 0:  mv = mraw[idx] != 0; break;
                case 1:  mv = ((const int*)mraw)[idx] != 0; break;
                case 2:  mv = ((const long long*)mraw)[idx] != 0LL; break;
                case 3:  mv = ((const float*)mraw)[idx] != 0.f; break;
                case 4:  mv = ((const double*)mraw)[idx] != 0.0; break;
                default: mv = ((const unsigned short*)mraw)[idx] != 0; break;
            }
            if (mv) { pos[b * SEQ + cnt] = t; ++cnt; }
            lastk[idx] = cnt - 1;
        }
        nmask[b] = cnt;
    }
}

// ---------- pack Whh (768x256 f32) -> column-major bf16 pairs ----------
// out2[q*768 + row] = { pack(W[row][4q],W[row][4q+1]), pack(W[row][4q+2],W[row][4q+3]) }
// Streaming read Wq2[q*G3 + tid] is fully coalesced across tid (rows).
__global__ __launch_bounds__(256) void k_pack(const float* __restrict__ W, uint2* __restrict__ out) {
    int i = blockIdx.x * 256 + threadIdx.x;
    if (i >= 64 * G3) return;
    int q = i / G3;
    int row = i % G3;
    const float* wr = W + (size_t)row * DB + 4 * q;
    unsigned int a = bf16rne(wr[0]) | (bf16rne(wr[1]) << 16);
    unsigned int b = bf16rne(wr[2]) | (bf16rne(wr[3]) << 16);
    out[i] = make_uint2(a, b);
}

// ---------- tiled NT GEMM: C[m][n] = bias[n] + sum_k A[m*K+k]*Bm[n*K+k] ----------
__global__ __launch_bounds__(256) void k_gemm_nt(int M, int N, int K,
        const float* __restrict__ A, const float* __restrict__ Bm,
        const float* __restrict__ bias, float* __restrict__ C) {
    __shared__ __align__(16) float As2[32][68];
    __shared__ __align__(16) float Bs2[32][68];
    int bm = blockIdx.y * 64, bn = blockIdx.x * 64;
    int tid = threadIdx.x;
    int tx = tid & 15, ty = tid >> 4;
    float acc[4][4] = {};
    for (int k0 = 0; k0 < K; k0 += 32) {
        for (int i = tid; i < 64 * 32; i += 256) {
            int r = i >> 5, c = i & 31;
            As2[c][r] = A[(size_t)(bm + r) * K + k0 + c];
            Bs2[c][r] = Bm[(size_t)(bn + r) * K + k0 + c];
        }
        __syncthreads();
#pragma unroll
        for (int kk = 0; kk < 32; ++kk) {
            float4 av = *reinterpret_cast<const float4*>(&As2[kk][ty * 4]);
            float4 bv = *reinterpret_cast<const float4*>(&Bs2[kk][tx * 4]);
            float a[4] = {av.x, av.y, av.z, av.w};
            float b[4] = {bv.x, bv.y, bv.z, bv.w};
#pragma unroll
            for (int i = 0; i < 4; ++i)
#pragma unroll
                for (int j = 0; j < 4; ++j) acc[i][j] += a[i] * b[j];
        }
        __syncthreads();
    }
#pragma unroll
    for (int i = 0; i < 4; ++i)
#pragma unroll
        for (int j = 0; j < 4; ++j)
            C[(size_t)(bm + ty * 4 + i) * N + bn + tx * 4 + j] = acc[i][j] + bias[bn + tx * 4 + j];
}

// ---------- K matrix: pooled onset + sinusoidal PE, project 32->256 ----------
__global__ __launch_bounds__(64) void k_keys(const float* __restrict__ onset,
        const float* __restrict__ Wk, const float* __restrict__ bk, float* __restrict__ Kmat) {
    int bt = blockIdx.x;
    int b = bt >> 10, t = bt & 1023;
    __shared__ float xin[CO];
    int tid = threadIdx.x;
    if (tid < CO) {
        float s = 0.f;
        const float* base = onset + ((size_t)b * TONS + (size_t)t * POOLN) * CO + tid;
#pragma unroll
        for (int p = 0; p < POOLN; ++p) s += base[p * CO];
        s *= (1.f / POOLN);
        int j = tid >> 1;
        float dv = expf(-logf(10000.f) * (float)j / 16.f);
        float ang = (float)t * dv;
        s += (tid & 1) ? cosf(ang) : sinf(ang);
        xin[tid] = s;
    }
    __syncthreads();
    for (int n = tid; n < DB; n += 64) {
        float acc = bk[n];
        const float* wr = Wk + (size_t)n * CO;
#pragma unroll
        for (int c = 0; c < CO; ++c) acc += xin[c] * wr[c];
        Kmat[(size_t)bt * DB + n] = acc;
    }
}

// ---------- phase B: per-chain note-GRU rollout, bf16 Whh streamed (coalesced) ----------
__global__ __launch_bounds__(768) void k_noteg(const uint2* __restrict__ Wq2,
        const float* __restrict__ bhh, const float* __restrict__ gi,
        const int* __restrict__ pos, const int* __restrict__ nmask, float* __restrict__ hend) {
    int c = blockIdx.x;
    int b = c >> 10, k = c & 1023;
    if (k >= nmask[b]) return;
    int s = (k == 0) ? 0 : pos[b * SEQ + k - 1] + 1;
    int e = pos[b * SEQ + k];
    int tid = threadIdx.x;
    __shared__ __align__(16) float hs[DB];
    __shared__ float ghs[G3];
    __shared__ float gxs[G3];
    float bh = bhh[tid];
    float h_reg = 0.f;
    if (tid < DB) hs[tid] = 0.f;
    __syncthreads();
    const float4* h4 = (const float4*)hs;
    const float* gip = gi + (size_t)(b * SEQ + s) * G3 + tid;
    for (int t = s; t < e; ++t) {
        float gpre = *gip;
        gip += G3;
        float ax = 0.f, ay = 0.f;
        if (t != s) {
#pragma unroll 8
            for (int q = 0; q < 64; ++q) {
                uint2 u = Wq2[q * G3 + tid];
                float4 hv = h4[q];
                ax += lof(u.x) * hv.x; ay += hif(u.x) * hv.y;
                ax += lof(u.y) * hv.z; ay += hif(u.y) * hv.w;
            }
        }
        ghs[tid] = bh + ax + ay;
        gxs[tid] = gpre;
        __syncthreads();
        if (tid < DB) {
            float r = 1.f / (1.f + expf(-(gxs[tid] + ghs[tid])));
            float z = 1.f / (1.f + expf(-(gxs[DB + tid] + ghs[DB + tid])));
            float n = tanhf(gxs[2 * DB + tid] + r * ghs[2 * DB + tid]);
            h_reg = (1.f - z) * n + z * h_reg;
            hs[tid] = h_reg;
        }
        __syncthreads();
    }
    if (tid < DB) hend[(size_t)c * DB + tid] = h_reg;
}

// ---------- phase C: per-batch bar-GRU chain, bf16 Whh streamed (coalesced) ----------
__global__ __launch_bounds__(768) void k_barg(const uint2* __restrict__ Wq2,
        const float* __restrict__ bhh, const float* __restrict__ gibar,
        const int* __restrict__ nmask, float* __restrict__ gall) {
    int b = blockIdx.x;
    int nm = nmask[b];
    int tid = threadIdx.x;
    __shared__ __align__(16) float hs[DB];
    __shared__ float ghs[G3];
    __shared__ float gxs[G3];
    float bh = bhh[tid];
    float g_reg = 0.f;
    if (tid < DB) hs[tid] = 0.f;
    __syncthreads();
    const float4* h4 = (const float4*)hs;
    const float* gip = gibar + (size_t)(b * SEQ) * G3 + tid;
    for (int k = 0; k < nm; ++k) {
        float gpre = *gip;
        gip += G3;
        float ax = 0.f, ay = 0.f;
        if (k != 0) {
#pragma unroll 8
            for (int q = 0; q < 64; ++q) {
                uint2 u = Wq2[q * G3 + tid];
                float4 hv = h4[q];
                ax += lof(u.x) * hv.x; ay += hif(u.x) * hv.y;
                ax += lof(u.y) * hv.z; ay += hif(u.y) * hv.w;
            }
        }
        ghs[tid] = bh + ax + ay;
        gxs[tid] = gpre;
        __syncthreads();
        if (tid < DB) {
            float r = 1.f / (1.f + expf(-(gxs[tid] + ghs[tid])));
            float z = 1.f / (1.f + expf(-(gxs[DB + tid] + ghs[DB + tid])));
            float n = tanhf(gxs[2 * DB + tid] + r * ghs[2 * DB + tid]);
            g_reg = (1.f - z) * n + z * g_reg;
            hs[tid] = g_reg;
            gall[(size_t)(b * SEQ + k) * DB + tid] = g_reg;
        }
        __syncthreads();
    }
}

// ---------- fill outputs: h_bar_carried, h_bar_final, zero com ----------
__global__ __launch_bounds__(256) void k_fill(const float* __restrict__ gall,
        const int* __restrict__ lastk, const int* __restrict__ nmask,
        float* __restrict__ out) {
    int bt = blockIdx.x;
    int b = bt >> 10, t = bt & 1023;
    int tid = threadIdx.x;
    int lk = lastk[bt];
    float v = (lk >= 0) ? gall[((size_t)b * SEQ + lk) * DB + tid] : 0.f;
    out[OUT_CARR + (size_t)bt * DB + tid] = v;
    if (tid == 0) out[bt] = 0.f;
    if (t == 0) {
        int nm = nmask[b];
        float fv = (nm > 0) ? gall[((size_t)b * SEQ + nm - 1) * DB + tid] : 0.f;
        out[OUT_FINAL + b * DB + tid] = fv;
    }
}

// ---------- attention + com at mask rows only ----------
__global__ __launch_bounds__(256) void k_attn(const float* __restrict__ gall,
        const float* __restrict__ Wq, const float* __restrict__ bq,
        const float* __restrict__ Kmat, const int* __restrict__ pos,
        const int* __restrict__ nmask, const float* __restrict__ pbs_ptr,
        float* __restrict__ out) {
    int c = blockIdx.x;
    int b = c >> 10, k = c & 1023;
    if (k >= nmask[b]) return;
    int trow = pos[b * SEQ + k];
    __shared__ float q[DB];
    __shared__ float grow[DB];
    __shared__ float sc[NH][TOCT];
    __shared__ float comh[NH];
    int tid = threadIdx.x;
    grow[tid] = gall[((size_t)b * SEQ + k) * DB + tid];
    __syncthreads();
    {
        float acc = bq[tid];
        const float* wr = Wq + (size_t)tid * DB;
#pragma unroll 4
        for (int j = 0; j < DB; ++j) acc += grow[j] * wr[j];
        q[tid] = acc;
    }
    __syncthreads();
    float pbs = *pbs_ptr;
    const float scale = 0.17677669529663687f; // 1/sqrt(32)
    for (int t = tid; t < TOCT; t += 256) {
        const float* kr = Kmat + ((size_t)b * TOCT + t) * DB;
        float tp = (float)t * (1.f / 1023.f);
#pragma unroll
        for (int h = 0; h < NH; ++h) {
            float acc = 0.f;
#pragma unroll
            for (int d = 0; d < DHD; ++d) acc += q[h * DHD + d] * kr[h * DHD + d];
            sc[h][t] = acc * scale - pbs * tp;
        }
    }
    __syncthreads();
    int hh = tid >> 5, l = tid & 31;
    float mx = -1e30f;
    for (int t = l; t < TOCT; t += 32) mx = fmaxf(mx, sc[hh][t]);
#pragma unroll
    for (int o = 16; o > 0; o >>= 1) mx = fmaxf(mx, __shfl_xor(mx, o, 32));
    float se = 0.f, sw = 0.f;
    for (int t = l; t < TOCT; t += 32) {
        float e = expf(sc[hh][t] - mx);
        se += e;
        sw += e * ((float)t * (1.f / 1023.f));
    }
#pragma unroll
    for (int o = 16; o > 0; o >>= 1) { se += __shfl_xor(se, o, 32); sw += __shfl_xor(sw, o, 32); }
    if (l == 0) comh[hh] = sw / se;
    __syncthreads();
    if (tid == 0) {
        float cm = 0.f;
#pragma unroll
        for (int h = 0; h < NH; ++h) cm += comh[h];
        out[b * SEQ + trow] = cm * (1.f / NH);
    }
}

extern "C" void kernel_launch(void* const* d_in, const int* in_sizes, int n_in,
                              void* d_out, int out_size, void* d_ws, size_t ws_size,
                              hipStream_t stream) {
    const float* te    = (const float*)d_in[0];
    const float* onset = (const float*)d_in[1];
    const unsigned char* mask = (const unsigned char*)d_in[2];
    const float* Wih_n = (const float*)d_in[3];
    const float* Whh_n = (const float*)d_in[4];
    const float* bih_n = (const float*)d_in[5];
    const float* bhh_n = (const float*)d_in[6];
    const float* Wih_b = (const float*)d_in[7];
    const float* Whh_b = (const float*)d_in[8];
    const float* bih_b = (const float*)d_in[9];
    const float* bhh_b = (const float*)d_in[10];
    const float* Wq    = (const float*)d_in[11];
    const float* bq    = (const float*)d_in[12];
    const float* Wk    = (const float*)d_in[13];
    const float* bk    = (const float*)d_in[14];
    const float* pbs   = (const float*)d_in[15];
    float* out = (float*)d_out;

    float* ws    = (float*)d_ws;
    float* gi    = ws + OFF_GI;
    float* gibar = ws + OFF_GIBAR;
    float* hend  = ws + OFF_HEND;
    float* gall  = ws + OFF_GALL;
    float* kmat  = ws + OFF_KMAT;
    uint2* wpn   = (uint2*)(ws + OFF_WPN);
    uint2* wpb   = (uint2*)(ws + OFF_WPB);
    int* ipos    = (int*)((char*)d_ws + OFF_INT_BYTES);
    int* ilastk  = ipos + NB * SEQ;
    int* inmask  = ilastk + NB * SEQ;

    k_scan<<<1, 256, 0, stream>>>(mask, ipos, ilastk, inmask);
    k_pack<<<192, 256, 0, stream>>>(Whh_n, wpn);
    k_pack<<<192, 256, 0, stream>>>(Whh_b, wpb);
    k_gemm_nt<<<dim3(G3 / 64, (NB * SEQ) / 64), 256, 0, stream>>>(NB * SEQ, G3, DM, te, Wih_n, bih_n, gi);
    k_keys<<<NB * TOCT, 64, 0, stream>>>(onset, Wk, bk, kmat);
    k_noteg<<<NB * SEQ, 768, 0, stream>>>(wpn, bhh_n, gi, ipos, inmask, hend);
    k_gemm_nt<<<dim3(G3 / 64, (NB * SEQ) / 64), 256, 0, stream>>>(NB * SEQ, G3, DB, hend, Wih_b, bih_b, gibar);
    k_barg<<<NB, 768, 0, stream>>>(wpb, bhh_b, gibar, inmask, gall);
    k_fill<<<NB * SEQ, 256, 0, stream>>>(gall, ilastk, inmask, out);
    k_attn<<<NB * SEQ, 256, 0, stream>>>(gall, Wq, bq, kmat, ipos, inmask, pbs, out);
}